// Round 15
// baseline (134.777 us; speedup 1.0000x reference)
//
#include <hip/hip_runtime.h>
#include <type_traits>

#define NQ 10
#define N_DEPTH 5
#define DIM 1024
#define BATCH 16384
#define IN_DIM 784
#define NGATES 50
#define KPAD 800      // Xb row length (bf16), cols 784..799 zero
#define KALLOC 832    // W2T row length = 13*64; W2 rows >=784 zero
#define NT 13         // K-tiles of 64 (13*64 = 832)

typedef float f32x2 __attribute__((ext_vector_type(2)));
typedef float f32x4 __attribute__((ext_vector_type(4)));
typedef short bf16x8 __attribute__((ext_vector_type(8)));
typedef unsigned u32x4 __attribute__((ext_vector_type(4)));

// ---------------------------------------------------------------------------
// Compile-time mask tables: CNOTs absorbed into GF(2)-linear index transform.
// ---------------------------------------------------------------------------
struct MaskTab {
  unsigned v[NGATES];
  unsigned p[NGATES];
  unsigned vz0, vz1;
};

constexpr MaskTab make_masks() {
  MaskTab t{};
  unsigned v[NQ], p[NQ];
  for (int i = 0; i < NQ; ++i) { v[i] = 1u << (9 - i); p[i] = 1u << (9 - i); }
  for (int d = 0; d < N_DEPTH; ++d) {
    for (int i = 0; i < NQ; ++i) {
      int c = i, tt = (i + 1) % NQ;
      v[tt] ^= v[c];
      p[c]  ^= p[tt];
    }
    for (int i = 0; i < NQ; ++i) {
      t.v[d * NQ + i] = v[i];
      t.p[d * NQ + i] = p[i];
    }
  }
  t.vz0 = v[0];
  t.vz1 = v[1];
  return t;
}

constexpr MaskTab MT = make_masks();
__constant__ MaskTab d_MT = make_masks();

// d = co*o + cp*q (complex), packed (re,im); 4 VOP3P instrs (verified r2-r14).
__device__ __forceinline__ f32x2 ampfma(f32x2 o, f32x2 q, f32x2 co, f32x2 cp) {
  f32x2 d;
  asm("v_pk_mul_f32 %0, %2, %1 op_sel:[0,0] op_sel_hi:[0,1]\n\t"
      "v_pk_fma_f32 %0, %2, %1, %0 op_sel:[1,1,0] op_sel_hi:[1,0,1] neg_lo:[1,0,0]\n\t"
      "v_pk_fma_f32 %0, %3, %4, %0 op_sel:[0,0,0] op_sel_hi:[0,1,1]\n\t"
      "v_pk_fma_f32 %0, %3, %4, %0 op_sel:[1,1,0] op_sel_hi:[1,0,1] neg_lo:[1,0,0]"
      : "=&v"(d)
      : "v"(o), "v"(co), "v"(cp), "v"(q));
  return d;
}

__device__ __forceinline__ float fxor(float x, unsigned m) {
  return __uint_as_float(__float_as_uint(x) ^ m);
}

__device__ __forceinline__ unsigned bf16pack(float lo, float hi) {
  unsigned a = __float_as_uint(lo), b = __float_as_uint(hi);
  unsigned ra = (a + 0x7fffu + ((a >> 16) & 1u)) >> 16;   // RNE
  unsigned rb = (b + 0x7fffu + ((b >> 16) & 1u)) >> 16;
  return (ra & 0xffffu) | (rb << 16);
}

__device__ __forceinline__ unsigned cvtpk(float a, float b) {
  unsigned d;
  asm("v_cvt_pk_bf16_f32 %0, %1, %2" : "=v"(d) : "v"(a), "v"(b));
  return d;
}

__device__ __forceinline__ void gll16(const void* g, void* l) {
  __builtin_amdgcn_global_load_lds(
      (const __attribute__((address_space(1))) void*)g,
      (__attribute__((address_space(3))) void*)l, 16, 0, 0);
}

// ---------------------------------------------------------------------------
// K0+K1 merged. build_w blocks FIRST (long-running, must dispatch early):
//   blocks [0, 832):     basis columns e_j -> W2[j][2m+c] bf16 (LDS ping-pong)
//   blocks [832, 7232):  X f32 [16384][784] -> Xb bf16 [16384][800]
// (verified r8-r14)
// ---------------------------------------------------------------------------
__global__ __launch_bounds__(256) void prep(const float* __restrict__ X,
                                            unsigned* __restrict__ Xb,
                                            const float* __restrict__ w,
                                            unsigned* __restrict__ W2u) {
  __shared__ f32x4 UL4[NGATES];
  __shared__ f32x2 S0[DIM];
  __shared__ f32x2 S1[DIM];

  const int tid = threadIdx.x;

  if (blockIdx.x >= 832) {
    // ---- xcvt part ----
    const int cid = (blockIdx.x - 832) * 256 + tid;   // 16384*100 chunk tasks
    const int row = cid / 100, c8 = cid - row * 100;
    u32x4 out;
    if (c8 < 98) {
      const float* src = X + (size_t)row * IN_DIM + c8 * 8;
      f32x4 v0 = *(const f32x4*)src;
      f32x4 v1 = *(const f32x4*)(src + 4);
      out = u32x4{cvtpk(v0.x, v0.y), cvtpk(v0.z, v0.w),
                  cvtpk(v1.x, v1.y), cvtpk(v1.z, v1.w)};
    } else {
      out = u32x4{0, 0, 0, 0};
    }
    *(u32x4*)(Xb + (size_t)row * (KPAD / 2) + c8 * 4) = out;
    return;
  }

  // ---- build_w part (verified r6-r14) ----
  if (tid < NGATES) {
    // qml.Rot(phi, theta, omega) = RZ(omega) RY(theta) RZ(phi)
    float phi = w[tid * 3 + 0], th = w[tid * 3 + 1], om = w[tid * 3 + 2];
    float ct = cosf(th * 0.5f), st = sinf(th * 0.5f);
    float aa = (phi + om) * 0.5f, bb = (phi - om) * 0.5f;
    float cA = cosf(aa), sA = sinf(aa), cB = cosf(bb), sB = sinf(bb);
    // u00 = e^{-ia} c ; u01 = -e^{+ib} s  (u11 = conj(u00), u10 = -conj(u01))
    UL4[tid] = f32x4{ ct * cA, -ct * sA, -st * cB, -st * sB };
  }

  const int j = blockIdx.x;                     // 0..831
  unsigned* rowp = W2u + (size_t)j * 1024;

  if (j >= IN_DIM) {                            // zero pad rows (uniform branch)
#pragma unroll
    for (int k = 0; k < 4; ++k) rowp[tid + k * 256] = 0u;
    return;
  }

#pragma unroll
  for (int k = 0; k < 4; ++k) {
    const int m = tid + k * 256;
    S0[m] = f32x2{(m == j) ? 1.0f : 0.0f, 0.0f};
  }
  __syncthreads();

  for (int g = 0; g < NGATES; ++g) {
    const f32x2* src = (g & 1) ? S1 : S0;
    f32x2* dst = (g & 1) ? S0 : S1;
    const f32x4 A = UL4[g];
    const unsigned v = d_MT.v[g];
    const unsigned p = d_MT.p[g];
#pragma unroll
    for (int k = 0; k < 4; ++k) {
      const int m = tid + k * 256;
      f32x2 o = src[m];
      f32x2 q = src[m ^ (int)p];
      const unsigned sg = (unsigned)(__popc((int)((unsigned)m & v)) & 1) << 31;
      const f32x2 co = {A.x, fxor(A.y, sg)};
      const f32x2 cp = {fxor(A.z, sg), A.w};
      dst[m] = ampfma(o, q, co, cp);
    }
    __syncthreads();
  }

  const f32x2* fin = S0;   // 50 gates (even) -> final state back in S0
#pragma unroll
  for (int k = 0; k < 4; ++k) {
    const int m = tid + k * 256;
    f32x2 a = fin[m];
    rowp[m] = bf16pack(a.x, a.y);
  }
}

// ---------------------------------------------------------------------------
// K2: transpose W2 [832][2048] -> W2T [2048][832] (bf16), 64x64 tiles.
// (verified r4-r14)
// ---------------------------------------------------------------------------
__global__ __launch_bounds__(256) void transpose_w(const unsigned* __restrict__ W2u,
                                                   unsigned* __restrict__ W2Tu) {
  __shared__ unsigned tile[64][33];
  const int j0 = blockIdx.x * 64;   // gridDim.x = 13
  const int n0 = blockIdx.y * 64;   // gridDim.y = 32
  const int t = threadIdx.x;
#pragma unroll
  for (int i = 0; i < 8; ++i) {
    const int idx = i * 256 + t;
    const int jr = idx >> 5, nc = idx & 31;
    tile[jr][nc] = W2u[(size_t)(j0 + jr) * 1024 + (n0 >> 1) + nc];
  }
  __syncthreads();
#pragma unroll
  for (int i = 0; i < 8; ++i) {
    const int idx = i * 256 + t;
    const int nr = idx >> 5, jc = idx & 31;
    const unsigned lo = tile[jc * 2][nr >> 1];
    const unsigned hi = tile[jc * 2 + 1][nr >> 1];
    const unsigned sh = (unsigned)(nr & 1) * 16u;
    const unsigned val = ((lo >> sh) & 0xffffu) | (((hi >> sh) & 0xffffu) << 16);
    W2Tu[(size_t)(n0 + nr) * (KALLOC / 2) + (j0 >> 1) + jc] = val;
  }
}

// ---------------------------------------------------------------------------
// K3 v13: r12 skeleton with ONE change: B (W2T, 3.4 MB, L2-resident) is NOT
// staged through LDS — B fragments load directly global->VGPR. Removes B's
// LDS write (64KB/tile) + LDS read (64KB/tile): LDS port traffic -40%, and
// B traffic moves to the VMEM pipe (overlaps LDS instead of contending).
// B loads issue at the top of each tile so L2 latency hides under the 24
// A ds_reads. A path unchanged: gll16, 2x32KB dbuf, 8-chunk XOR swizzle,
// one barrier/tile, mfma_f32_16x16x32_bf16, BK=64, 13 tiles.
// ---------------------------------------------------------------------------
__global__ __launch_bounds__(512) void gemm_fused(const unsigned short* __restrict__ Xb,
                                                  const unsigned short* __restrict__ W2T,
                                                  float* __restrict__ accb) {
  __shared__ u32x4 lds4[4096];   // 64 KB: 2 x (A 32KB)
  char* lds = (char*)lds4;

  const int tid = threadIdx.x;
  const int orig = blockIdx.x;                    // 512 blocks
  const int bx = (orig & 7) * 64 + (orig >> 3);   // XCD-chunked (512%8==0)
  const int mb = bx >> 3, nb = bx & 7;
  const int m0 = mb * 256, n0 = nb * 256;
  const int lane = tid & 63, wv = tid >> 6;
  const int wm = wv >> 2, wn = wv & 3;

  // A stage lane geometry (verified r12): unit g covers rows g*8..g*8+7
  // (128B rows); lane l -> LDS (row_local = l>>3, chunk' = l&7); source
  // global chunk c = (l&7) ^ (l>>3) so that phys chunk' = c ^ (row&7).
  const int lrow = lane >> 3;                     // 0..7
  const int lc = (lane & 7) ^ lrow;               // source chunk 0..7

  auto stageA = [&](int t) {
    char* Ab = lds + (t & 1) * 32768;
    int colA = t * 64 + lc * 8;
    if (colA > 792) colA = 792;                   // clamp: j>=800 pairs 0-B
#pragma unroll
    for (int i = 0; i < 4; ++i) {                 // A: 4 units/wave (32 total)
      const int g = wv * 4 + i;
      const int row = g * 8 + lrow;
      gll16(Xb + (size_t)(m0 + row) * KPAD + colA, Ab + g * 1024);
    }
  };

  stageA(0);
  asm volatile("s_waitcnt vmcnt(0)" ::: "memory");
  __builtin_amdgcn_s_barrier();

  f32x4 acc[8][4];
#pragma unroll
  for (int fm = 0; fm < 8; ++fm)
#pragma unroll
    for (int fn = 0; fn < 4; ++fn) acc[fm][fn] = f32x4{0, 0, 0, 0};

  const int kc = lane >> 4;                       // k-chunk-of-8 within K=32
  // B-fragment global base: row = n0 + wn*64 + f*16 + (lane&15),
  // col elems = t*64 + kh*32 + kc*8 (16B aligned: 832 % 8 == 0).
  const unsigned short* Bp =
      W2T + (size_t)(n0 + wn * 64 + (lane & 15)) * KALLOC + kc * 8;

  for (int t = 0; t < NT; ++t) {
    const char* Ab = lds + (t & 1) * 32768;

    // B loads FIRST (8 global 16B loads; L2-resident rows)
    bf16x8 bf0[4], bf1[4];
#pragma unroll
    for (int f = 0; f < 4; ++f) {
      const unsigned short* r = Bp + (size_t)(f * 16) * KALLOC + t * 64;
      bf0[f] = *(const bf16x8*)(r);
      bf1[f] = *(const bf16x8*)(r + 32);
    }

    if (t < NT - 1) stageA(t + 1);                // -> other buffer (safe)

    bf16x8 af0[8], af1[8];
#pragma unroll
    for (int f = 0; f < 8; ++f) {
      const int ar = wm * 128 + f * 16 + (lane & 15);
      af0[f] = *(const bf16x8*)(Ab + ar * 128 + ((kc ^ (ar & 7)) * 16));
    }
#pragma unroll
    for (int f = 0; f < 8; ++f) {
      const int ar = wm * 128 + f * 16 + (lane & 15);
      af1[f] = *(const bf16x8*)(Ab + ar * 128 + (((4 + kc) ^ (ar & 7)) * 16));
    }

    __builtin_amdgcn_s_setprio(1);
#pragma unroll
    for (int fm = 0; fm < 8; ++fm)
#pragma unroll
      for (int fn = 0; fn < 4; ++fn)
        acc[fm][fn] = __builtin_amdgcn_mfma_f32_16x16x32_bf16(
            af0[fm], bf0[fn], acc[fm][fn], 0, 0, 0);
    __builtin_amdgcn_s_setprio(0);

    __builtin_amdgcn_s_setprio(1);
#pragma unroll
    for (int fm = 0; fm < 8; ++fm)
#pragma unroll
      for (int fn = 0; fn < 4; ++fn)
        acc[fm][fn] = __builtin_amdgcn_mfma_f32_16x16x32_bf16(
            af1[fm], bf1[fn], acc[fm][fn], 0, 0, 0);
    __builtin_amdgcn_s_setprio(0);

    if (t < NT - 1) {
      asm volatile("s_waitcnt vmcnt(0)" ::: "memory");  // next A tile landed
      __builtin_amdgcn_sched_barrier(0);
      __builtin_amdgcn_s_barrier();
    }
  }

  // ---- epilogue: per-sample (n2, z0, z1) partials (verified r4-r14) ----
  constexpr unsigned vz0 = MT.vz0, vz1 = MT.vz1;
  const int colbase = n0 + wn * 64 + (lane & 15);
#pragma unroll
  for (int fm = 0; fm < 8; ++fm) {
    float sn[4] = {0, 0, 0, 0}, s0[4] = {0, 0, 0, 0}, s1[4] = {0, 0, 0, 0};
#pragma unroll
    for (int fn = 0; fn < 4; ++fn) {
      const int st = (colbase + fn * 16) >> 1;     // quantum state index
      const float g0 = 1.0f - 2.0f * (float)(__popc(st & (int)vz0) & 1);
      const float g1 = 1.0f - 2.0f * (float)(__popc(st & (int)vz1) & 1);
#pragma unroll
      for (int r = 0; r < 4; ++r) {
        const float vv = acc[fm][fn][r];
        const float wq = vv * vv;
        sn[r] += wq;
        s0[r] = fmaf(g0, wq, s0[r]);
        s1[r] = fmaf(g1, wq, s1[r]);
      }
    }
#pragma unroll
    for (int off = 1; off < 16; off <<= 1) {
#pragma unroll
      for (int r = 0; r < 4; ++r) {
        sn[r] += __shfl_xor(sn[r], off);
        s0[r] += __shfl_xor(s0[r], off);
        s1[r] += __shfl_xor(s1[r], off);
      }
    }
    if ((lane & 15) == 0) {
#pragma unroll
      for (int r = 0; r < 4; ++r) {
        const int m = m0 + wm * 128 + fm * 16 + (lane >> 4) * 4 + r;
        *(f32x4*)(accb + ((size_t)nb * BATCH + m) * 4) =
            f32x4{sn[r], s0[r], s1[r], 0.0f};
      }
    }
  }
}

// ---------------------------------------------------------------------------
// K4/K5: per-sample loss + mean reduction. (verified r8-r12)
// ---------------------------------------------------------------------------
__global__ __launch_bounds__(256) void loss_partial(const float* __restrict__ accb,
                                                    const int* __restrict__ y,
                                                    float* __restrict__ partial) {
  const int s = blockIdx.x * 256 + threadIdx.x;
  float n2 = 0.0f, z0 = 0.0f, z1 = 0.0f;
#pragma unroll
  for (int nb = 0; nb < 8; ++nb) {
    f32x4 v = *(const f32x4*)(accb + ((size_t)nb * BATCH + s) * 4);
    n2 += v.x; z0 += v.y; z1 += v.z;
  }
  const float inv = 1.0f / n2;
  const float l0 = z0 * inv, l1 = z1 * inv;
  const float mx = fmaxf(l0, l1);
  const float lse = mx + logf(expf(l0 - mx) + expf(l1 - mx));
  float loss = lse - ((y[s] == 0) ? l0 : l1);

  __shared__ float sm[256];
  sm[threadIdx.x] = loss;
  __syncthreads();
  for (int st = 128; st > 0; st >>= 1) {
    if (threadIdx.x < st) sm[threadIdx.x] += sm[threadIdx.x + st];
    __syncthreads();
  }
  if (threadIdx.x == 0) partial[blockIdx.x] = sm[0];
}

__global__ __launch_bounds__(64) void loss_final(const float* __restrict__ partial,
                                                 float* __restrict__ out) {
  float v = partial[threadIdx.x];
#pragma unroll
  for (int off = 1; off < 64; off <<= 1) v += __shfl_xor(v, off);
  if (threadIdx.x == 0) out[0] = v * (1.0f / (float)BATCH);
}

// ---------------------------------------------------------------------------
extern "C" void kernel_launch(void* const* d_in, const int* in_sizes, int n_in,
                              void* d_out, int out_size, void* d_ws, size_t ws_size,
                              hipStream_t stream) {
  const float* x = (const float*)d_in[0];   // [16384, 784] f32
  const float* w = (const float*)d_in[1];   // [5, 10, 3] f32
  const int*   y = (const int*)d_in[2];     // [16384] i32

  char* ws = (char*)d_ws;
  unsigned* Xb   = (unsigned*)ws;                    // 16384*800*2 = 26.2 MB
  unsigned* W2u  = (unsigned*)(ws + 26214400);       // 832*1024*4  = 3.41 MB
  unsigned* W2Tu = (unsigned*)(ws + 29622272);       // 2048*832*2  = 3.41 MB
  // after transpose_w, W2u region is dead -> reuse for accb (2 MB)
  float*    accb = (float*)(ws + 26214400);          // 8*16384*4 f32 = 2 MB
  float* partial = (float*)(ws + 33030144);          // 64 f32

  prep<<<7232, 256, 0, stream>>>(x, Xb, w, W2u);
  transpose_w<<<dim3(13, 32), 256, 0, stream>>>(W2u, W2Tu);
  gemm_fused<<<512, 512, 0, stream>>>((const unsigned short*)Xb,
                                      (const unsigned short*)W2Tu, accb);
  loss_partial<<<BATCH / 256, 256, 0, stream>>>(accb, y, partial);
  loss_final<<<1, 64, 0, stream>>>(partial, (float*)d_out);
}

// Round 16
// 89.265 us; speedup vs baseline: 1.5098x; 1.5098x over previous
//
#include <hip/hip_runtime.h>
#include <type_traits>

#define NQ 10
#define N_DEPTH 5
#define DIM 1024
#define BATCH 16384
#define IN_DIM 784
#define NGATES 50
#define KPAD 800      // Xb row length (bf16), cols 784..799 zero
#define KALLOC 832    // W2T row length = 13*64; W2 rows >=784 zero
#define NT 13         // K-tiles of 64 (13*64 = 832)
#define NSLOT 768     // kept complex amp rows (p0|p1 = 1), group-blocked
#define NB 6          // gemm n-blocks (1536 bf16 cols / 256)

typedef float f32x2 __attribute__((ext_vector_type(2)));
typedef float f32x4 __attribute__((ext_vector_type(4)));
typedef short bf16x8 __attribute__((ext_vector_type(8)));
typedef unsigned u32x4 __attribute__((ext_vector_type(4)));

// ---------------------------------------------------------------------------
// Compile-time mask tables: CNOTs absorbed into GF(2)-linear index transform.
// ---------------------------------------------------------------------------
struct MaskTab {
  unsigned v[NGATES];
  unsigned p[NGATES];
  unsigned vz0, vz1;
};

constexpr MaskTab make_masks() {
  MaskTab t{};
  unsigned v[NQ], p[NQ];
  for (int i = 0; i < NQ; ++i) { v[i] = 1u << (9 - i); p[i] = 1u << (9 - i); }
  for (int d = 0; d < N_DEPTH; ++d) {
    for (int i = 0; i < NQ; ++i) {
      int c = i, tt = (i + 1) % NQ;
      v[tt] ^= v[c];
      p[c]  ^= p[tt];
    }
    for (int i = 0; i < NQ; ++i) {
      t.v[d * NQ + i] = v[i];
      t.p[d * NQ + i] = p[i];
    }
  }
  t.vz0 = v[0];
  t.vz1 = v[1];
  return t;
}

constexpr MaskTab MT = make_masks();
__constant__ MaskTab d_MT = make_masks();

// Permutation: state m -> output slot. Groups of 256 complex slots:
//   A [0,256):  p0=1, p1=0       (counts toward S0 only)
//   B [256,512): p0=0, p1=1      (S1 only)
//   C [512,768): p0=1, p1=1      (both)
//   dropped: p0=p1=0 (not needed; n2 = |x|^2 by unitarity)
// z0 = n2 - 2(SA+SC), z1 = n2 - 2(SB+SC).
struct PermTab { short slot[DIM]; };
constexpr PermTab make_perm() {
  PermTab t{};
  int a = 0, b = 256, c = 512;
  for (int m = 0; m < DIM; ++m) {
    const int p0 = __builtin_popcount((unsigned)m & MT.vz0) & 1;
    const int p1 = __builtin_popcount((unsigned)m & MT.vz1) & 1;
    if (p0 && !p1)      t.slot[m] = (short)a++;
    else if (!p0 && p1) t.slot[m] = (short)b++;
    else if (p0 && p1)  t.slot[m] = (short)c++;
    else                t.slot[m] = -1;
  }
  return t;
}
__constant__ PermTab d_PT = make_perm();

// d = co*o + cp*q (complex), packed (re,im); 4 VOP3P instrs (verified r2-r15).
__device__ __forceinline__ f32x2 ampfma(f32x2 o, f32x2 q, f32x2 co, f32x2 cp) {
  f32x2 d;
  asm("v_pk_mul_f32 %0, %2, %1 op_sel:[0,0] op_sel_hi:[0,1]\n\t"
      "v_pk_fma_f32 %0, %2, %1, %0 op_sel:[1,1,0] op_sel_hi:[1,0,1] neg_lo:[1,0,0]\n\t"
      "v_pk_fma_f32 %0, %3, %4, %0 op_sel:[0,0,0] op_sel_hi:[0,1,1]\n\t"
      "v_pk_fma_f32 %0, %3, %4, %0 op_sel:[1,1,0] op_sel_hi:[1,0,1] neg_lo:[1,0,0]"
      : "=&v"(d)
      : "v"(o), "v"(co), "v"(cp), "v"(q));
  return d;
}

__device__ __forceinline__ float fxor(float x, unsigned m) {
  return __uint_as_float(__float_as_uint(x) ^ m);
}

__device__ __forceinline__ unsigned bf16pack(float lo, float hi) {
  unsigned a = __float_as_uint(lo), b = __float_as_uint(hi);
  unsigned ra = (a + 0x7fffu + ((a >> 16) & 1u)) >> 16;   // RNE
  unsigned rb = (b + 0x7fffu + ((b >> 16) & 1u)) >> 16;
  return (ra & 0xffffu) | (rb << 16);
}

__device__ __forceinline__ unsigned cvtpk(float a, float b) {
  unsigned d;
  asm("v_cvt_pk_bf16_f32 %0, %1, %2" : "=v"(d) : "v"(a), "v"(b));
  return d;
}

__device__ __forceinline__ void gll16(const void* g, void* l) {
  __builtin_amdgcn_global_load_lds(
      (const __attribute__((address_space(1))) void*)g,
      (__attribute__((address_space(3))) void*)l, 16, 0, 0);
}

// ---------------------------------------------------------------------------
// K0+K1 merged. build_w blocks FIRST (long-running):
//   blocks [0, 832):      basis columns e_j -> W2[j][768 slots] bf16 pairs
//   blocks [832, 2880):   xcvt 8 rows/block: X f32 -> Xb bf16 + xn2 = |x|^2
// ---------------------------------------------------------------------------
__global__ __launch_bounds__(256) void prep(const float* __restrict__ X,
                                            unsigned* __restrict__ Xb,
                                            float* __restrict__ xn2,
                                            const float* __restrict__ w,
                                            unsigned* __restrict__ W2u) {
  __shared__ f32x4 UL4[NGATES];
  __shared__ f32x2 S0[DIM];
  __shared__ f32x2 S1[DIM];

  const int tid = threadIdx.x;

  if (blockIdx.x >= 832) {
    // ---- xcvt + row-norm part: 8 rows per block, 32 lanes per row ----
    const int row = (blockIdx.x - 832) * 8 + (tid >> 5);
    const int l32 = tid & 31;
    const float* src = X + (size_t)row * IN_DIM;
    unsigned* dst = Xb + (size_t)row * (KPAD / 2);
    float ssq = 0.0f;
    for (int c = l32; c < 100; c += 32) {
      u32x4 out;
      if (c < 98) {
        f32x4 v0 = *(const f32x4*)(src + c * 8);
        f32x4 v1 = *(const f32x4*)(src + c * 8 + 4);
        ssq += v0.x * v0.x + v0.y * v0.y + v0.z * v0.z + v0.w * v0.w +
               v1.x * v1.x + v1.y * v1.y + v1.z * v1.z + v1.w * v1.w;
        out = u32x4{cvtpk(v0.x, v0.y), cvtpk(v0.z, v0.w),
                    cvtpk(v1.x, v1.y), cvtpk(v1.z, v1.w)};
      } else {
        out = u32x4{0, 0, 0, 0};
      }
      *(u32x4*)(dst + c * 4) = out;
    }
#pragma unroll
    for (int off = 1; off < 32; off <<= 1) ssq += __shfl_xor(ssq, off);
    if (l32 == 0) xn2[row] = ssq;
    return;
  }

  // ---- build_w part (gate loop verified r6-r15) ----
  if (tid < NGATES) {
    // qml.Rot(phi, theta, omega) = RZ(omega) RY(theta) RZ(phi)
    float phi = w[tid * 3 + 0], th = w[tid * 3 + 1], om = w[tid * 3 + 2];
    float ct = cosf(th * 0.5f), st = sinf(th * 0.5f);
    float aa = (phi + om) * 0.5f, bb = (phi - om) * 0.5f;
    float cA = cosf(aa), sA = sinf(aa), cB = cosf(bb), sB = sinf(bb);
    // u00 = e^{-ia} c ; u01 = -e^{+ib} s  (u11 = conj(u00), u10 = -conj(u01))
    UL4[tid] = f32x4{ ct * cA, -ct * sA, -st * cB, -st * sB };
  }

  const int j = blockIdx.x;                     // 0..831
  unsigned* rowp = W2u + (size_t)j * NSLOT;

  if (j >= IN_DIM) {                            // zero pad rows (uniform branch)
#pragma unroll
    for (int k = 0; k < 3; ++k) rowp[tid + k * 256] = 0u;
    return;
  }

#pragma unroll
  for (int k = 0; k < 4; ++k) {
    const int m = tid + k * 256;
    S0[m] = f32x2{(m == j) ? 1.0f : 0.0f, 0.0f};
  }
  __syncthreads();

  for (int g = 0; g < NGATES; ++g) {
    const f32x2* src = (g & 1) ? S1 : S0;
    f32x2* dst = (g & 1) ? S0 : S1;
    const f32x4 A = UL4[g];
    const unsigned v = d_MT.v[g];
    const unsigned p = d_MT.p[g];
#pragma unroll
    for (int k = 0; k < 4; ++k) {
      const int m = tid + k * 256;
      f32x2 o = src[m];
      f32x2 q = src[m ^ (int)p];
      const unsigned sg = (unsigned)(__popc((int)((unsigned)m & v)) & 1) << 31;
      const f32x2 co = {A.x, fxor(A.y, sg)};
      const f32x2 cp = {fxor(A.z, sg), A.w};
      dst[m] = ampfma(o, q, co, cp);
    }
    __syncthreads();
  }

  const f32x2* fin = S0;   // 50 gates (even) -> final state back in S0
#pragma unroll
  for (int k = 0; k < 4; ++k) {
    const int m = tid + k * 256;
    const int s = d_PT.slot[m];
    f32x2 a = fin[m];
    if (s >= 0) rowp[s] = bf16pack(a.x, a.y);
  }
}

// ---------------------------------------------------------------------------
// K2: transpose W2 [832][1536 bf16] -> W2T [1536][832] (bf16), 64x64 tiles.
// (structure verified r4-r15; row length 1024 -> 768 u32)
// ---------------------------------------------------------------------------
__global__ __launch_bounds__(256) void transpose_w(const unsigned* __restrict__ W2u,
                                                   unsigned* __restrict__ W2Tu) {
  __shared__ unsigned tile[64][33];
  const int j0 = blockIdx.x * 64;   // gridDim.x = 13
  const int n0 = blockIdx.y * 64;   // gridDim.y = 24
  const int t = threadIdx.x;
#pragma unroll
  for (int i = 0; i < 8; ++i) {
    const int idx = i * 256 + t;
    const int jr = idx >> 5, nc = idx & 31;
    tile[jr][nc] = W2u[(size_t)(j0 + jr) * NSLOT + (n0 >> 1) + nc];
  }
  __syncthreads();
#pragma unroll
  for (int i = 0; i < 8; ++i) {
    const int idx = i * 256 + t;
    const int nr = idx >> 5, jc = idx & 31;
    const unsigned lo = tile[jc * 2][nr >> 1];
    const unsigned hi = tile[jc * 2 + 1][nr >> 1];
    const unsigned sh = (unsigned)(nr & 1) * 16u;
    const unsigned val = ((lo >> sh) & 0xffffu) | (((hi >> sh) & 0xffffu) << 16);
    W2Tu[(size_t)(n0 + nr) * (KALLOC / 2) + (j0 >> 1) + jc] = val;
  }
}

// ---------------------------------------------------------------------------
// K3 v14: r12-exact gemm structure (best measured, 0 conflicts), N 2048->1536
// (6 nb blocks, grid 384). Epilogue: each nb tile is group-uniform, so it
// reduces to a single scalar sum |out|^2 per sample -> accb[nb][m].
// ---------------------------------------------------------------------------
__global__ __launch_bounds__(512) void gemm_fused(const unsigned short* __restrict__ Xb,
                                                  const unsigned short* __restrict__ W2T,
                                                  float* __restrict__ accb) {
  __shared__ u32x4 lds4[8192];   // 128 KB
  char* lds = (char*)lds4;

  const int tid = threadIdx.x;
  const int orig = blockIdx.x;                    // 384 blocks
  const int bx = (orig & 7) * 48 + (orig >> 3);   // XCD-chunked (384%8==0)
  const int mb = bx / NB, nb = bx % NB;
  const int m0 = mb * 256, n0 = nb * 256;
  const int lane = tid & 63, wv = tid >> 6;
  const int wm = wv >> 2, wn = wv & 3;

  // stage lane geometry (verified r12): unit g covers rows g*8..g*8+7
  // (128B rows); lane l -> LDS (row_local = l>>3, chunk' = l&7); source
  // global chunk c = (l&7) ^ (l>>3) so that phys chunk' = c ^ (row&7).
  const int lrow = lane >> 3;                     // 0..7
  const int lc = (lane & 7) ^ lrow;               // source chunk 0..7

  auto stage = [&](int t) {
    char* Ab = lds + (t & 1) * 65536;
    char* Bb = Ab + 32768;
    int colA = t * 64 + lc * 8;
    if (colA > 792) colA = 792;                   // clamp: j>=800 pairs 0-B
    const int colB = t * 64 + lc * 8;
#pragma unroll
    for (int i = 0; i < 4; ++i) {                 // A: 4 units/wave (32 total)
      const int g = wv * 4 + i;
      const int row = g * 8 + lrow;
      gll16(Xb + (size_t)(m0 + row) * KPAD + colA, Ab + g * 1024);
    }
#pragma unroll
    for (int i = 0; i < 4; ++i) {                 // B: 4 units/wave
      const int g = wv * 4 + i;
      const int row = g * 8 + lrow;
      gll16(W2T + (size_t)(n0 + row) * KALLOC + colB, Bb + g * 1024);
    }
  };

  stage(0);
  asm volatile("s_waitcnt vmcnt(0)" ::: "memory");
  __builtin_amdgcn_s_barrier();

  f32x4 acc[8][4];
#pragma unroll
  for (int fm = 0; fm < 8; ++fm)
#pragma unroll
    for (int fn = 0; fn < 4; ++fn) acc[fm][fn] = f32x4{0, 0, 0, 0};

  const int kc = lane >> 4;                       // k-chunk-of-8 within K=32

  for (int t = 0; t < NT; ++t) {
    const char* Ab = lds + (t & 1) * 65536;
    const char* Bb = Ab + 32768;

    bf16x8 af0[8], bf0[4], af1[8], bf1[4];
    // kh=0 operand reads (12 ds_read_b128)
#pragma unroll
    for (int f = 0; f < 8; ++f) {
      const int ar = wm * 128 + f * 16 + (lane & 15);
      af0[f] = *(const bf16x8*)(Ab + ar * 128 + ((kc ^ (ar & 7)) * 16));
    }
#pragma unroll
    for (int f = 0; f < 4; ++f) {
      const int br = wn * 64 + f * 16 + (lane & 15);
      bf0[f] = *(const bf16x8*)(Bb + br * 128 + ((kc ^ (br & 7)) * 16));
    }
    if (t < NT - 1) stage(t + 1);                 // -> other buffer (safe)
    // kh=1 operand reads — overlap kh0's MFMA via counted lgkm waits
#pragma unroll
    for (int f = 0; f < 8; ++f) {
      const int ar = wm * 128 + f * 16 + (lane & 15);
      af1[f] = *(const bf16x8*)(Ab + ar * 128 + (((4 + kc) ^ (ar & 7)) * 16));
    }
#pragma unroll
    for (int f = 0; f < 4; ++f) {
      const int br = wn * 64 + f * 16 + (lane & 15);
      bf1[f] = *(const bf16x8*)(Bb + br * 128 + (((4 + kc) ^ (br & 7)) * 16));
    }

    __builtin_amdgcn_s_setprio(1);
#pragma unroll
    for (int fm = 0; fm < 8; ++fm)
#pragma unroll
      for (int fn = 0; fn < 4; ++fn)
        acc[fm][fn] = __builtin_amdgcn_mfma_f32_16x16x32_bf16(
            af0[fm], bf0[fn], acc[fm][fn], 0, 0, 0);
    __builtin_amdgcn_s_setprio(0);

    __builtin_amdgcn_s_setprio(1);
#pragma unroll
    for (int fm = 0; fm < 8; ++fm)
#pragma unroll
      for (int fn = 0; fn < 4; ++fn)
        acc[fm][fn] = __builtin_amdgcn_mfma_f32_16x16x32_bf16(
            af1[fm], bf1[fn], acc[fm][fn], 0, 0, 0);
    __builtin_amdgcn_s_setprio(0);

    if (t < NT - 1) {
      asm volatile("s_waitcnt vmcnt(0)" ::: "memory");  // next tile landed
      __builtin_amdgcn_sched_barrier(0);
      __builtin_amdgcn_s_barrier();
    }
  }

  // ---- epilogue: per-sample sum |out|^2 for this nb (group-uniform) ----
#pragma unroll
  for (int fm = 0; fm < 8; ++fm) {
    float sn[4] = {0, 0, 0, 0};
#pragma unroll
    for (int fn = 0; fn < 4; ++fn) {
#pragma unroll
      for (int r = 0; r < 4; ++r) {
        const float vv = acc[fm][fn][r];
        sn[r] = fmaf(vv, vv, sn[r]);
      }
    }
#pragma unroll
    for (int off = 1; off < 16; off <<= 1) {
#pragma unroll
      for (int r = 0; r < 4; ++r) sn[r] += __shfl_xor(sn[r], off);
    }
    if ((lane & 15) == 0) {
#pragma unroll
      for (int r = 0; r < 4; ++r) {
        const int m = m0 + wm * 128 + fm * 16 + (lane >> 4) * 4 + r;
        accb[(size_t)nb * BATCH + m] = sn[r];
      }
    }
  }
}

// ---------------------------------------------------------------------------
// K4/K5: per-sample loss + mean reduction.
// z0 = n2 - 2(SA+SC), z1 = n2 - 2(SB+SC); n2 = |x|^2 (exact, from prep).
// ---------------------------------------------------------------------------
__global__ __launch_bounds__(256) void loss_partial(const float* __restrict__ accb,
                                                    const float* __restrict__ xn2,
                                                    const int* __restrict__ y,
                                                    float* __restrict__ partial) {
  const int s = blockIdx.x * 256 + threadIdx.x;
  const float SA = accb[0 * BATCH + s] + accb[1 * BATCH + s];
  const float SB = accb[2 * BATCH + s] + accb[3 * BATCH + s];
  const float SC = accb[4 * BATCH + s] + accb[5 * BATCH + s];
  const float n2 = xn2[s];
  const float z0 = n2 - 2.0f * (SA + SC);
  const float z1 = n2 - 2.0f * (SB + SC);
  const float inv = 1.0f / n2;
  const float l0 = z0 * inv, l1 = z1 * inv;
  const float mx = fmaxf(l0, l1);
  const float lse = mx + logf(expf(l0 - mx) + expf(l1 - mx));
  float loss = lse - ((y[s] == 0) ? l0 : l1);

  __shared__ float sm[256];
  sm[threadIdx.x] = loss;
  __syncthreads();
  for (int st = 128; st > 0; st >>= 1) {
    if (threadIdx.x < st) sm[threadIdx.x] += sm[threadIdx.x + st];
    __syncthreads();
  }
  if (threadIdx.x == 0) partial[blockIdx.x] = sm[0];
}

__global__ __launch_bounds__(64) void loss_final(const float* __restrict__ partial,
                                                 float* __restrict__ out) {
  float v = partial[threadIdx.x];
#pragma unroll
  for (int off = 1; off < 64; off <<= 1) v += __shfl_xor(v, off);
  if (threadIdx.x == 0) out[0] = v * (1.0f / (float)BATCH);
}

// ---------------------------------------------------------------------------
extern "C" void kernel_launch(void* const* d_in, const int* in_sizes, int n_in,
                              void* d_out, int out_size, void* d_ws, size_t ws_size,
                              hipStream_t stream) {
  const float* x = (const float*)d_in[0];   // [16384, 784] f32
  const float* w = (const float*)d_in[1];   // [5, 10, 3] f32
  const int*   y = (const int*)d_in[2];     // [16384] i32

  char* ws = (char*)d_ws;
  unsigned* Xb   = (unsigned*)ws;                    // 16384*800*2 = 26.2 MB
  unsigned* W2u  = (unsigned*)(ws + 26214400);       // 832*768*4   = 2.56 MB
  unsigned* W2Tu = (unsigned*)(ws + 29622272);       // 1536*832*2  = 2.56 MB
  float*    xn2  = (float*)(ws + 32178176);          // 16384*4 = 64 KB
  // after transpose_w, W2u region is dead -> reuse for accb (384 KB)
  float*    accb = (float*)(ws + 26214400);          // 6*16384*4 f32
  float* partial = (float*)(ws + 33030144);          // 64 f32

  prep<<<2880, 256, 0, stream>>>(x, Xb, xn2, w, W2u);
  transpose_w<<<dim3(13, 24), 256, 0, stream>>>(W2u, W2Tu);
  gemm_fused<<<384, 512, 0, stream>>>((const unsigned short*)Xb,
                                      (const unsigned short*)W2Tu, accb);
  loss_partial<<<BATCH / 256, 256, 0, stream>>>(accb, xn2, y, partial);
  loss_final<<<1, 64, 0, stream>>>(partial, (float*)d_out);
}

// Round 17
// 87.420 us; speedup vs baseline: 1.5417x; 1.0211x over previous
//
#include <hip/hip_runtime.h>
#include <type_traits>

#define NQ 10
#define N_DEPTH 5
#define DIM 1024
#define BATCH 16384
#define IN_DIM 784
#define NGATES 50
#define KALLOC 832    // fp8 row length (13*64); cols >=784 zero
#define NT 13         // K-tiles of 64
#define NSLOT 768     // kept complex amp slots (p0|p1), group-blocked
#define NB 6          // gemm n-blocks (1536 fp8 cols / 256)

typedef float f32x2 __attribute__((ext_vector_type(2)));
typedef float f32x4 __attribute__((ext_vector_type(4)));
typedef unsigned u32x4 __attribute__((ext_vector_type(4)));

// ---------------------------------------------------------------------------
// Compile-time mask tables: CNOTs absorbed into GF(2)-linear index transform.
// ---------------------------------------------------------------------------
struct MaskTab {
  unsigned v[NGATES];
  unsigned p[NGATES];
  unsigned vz0, vz1;
};

constexpr MaskTab make_masks() {
  MaskTab t{};
  unsigned v[NQ], p[NQ];
  for (int i = 0; i < NQ; ++i) { v[i] = 1u << (9 - i); p[i] = 1u << (9 - i); }
  for (int d = 0; d < N_DEPTH; ++d) {
    for (int i = 0; i < NQ; ++i) {
      int c = i, tt = (i + 1) % NQ;
      v[tt] ^= v[c];
      p[c]  ^= p[tt];
    }
    for (int i = 0; i < NQ; ++i) {
      t.v[d * NQ + i] = v[i];
      t.p[d * NQ + i] = p[i];
    }
  }
  t.vz0 = v[0];
  t.vz1 = v[1];
  return t;
}

constexpr MaskTab MT = make_masks();
__constant__ MaskTab d_MT = make_masks();

// Permutation: state m -> slot. Groups of 256 complex slots:
//   A [0,256): p0=1,p1=0   B [256,512): p0=0,p1=1   C [512,768): p0=1,p1=1
// z0 = n2 - 2(SA+SC), z1 = n2 - 2(SB+SC); n2 = |x|^2 exact (unitarity).
struct PermTab { short slot[DIM]; };
constexpr PermTab make_perm() {
  PermTab t{};
  int a = 0, b = 256, c = 512;
  for (int m = 0; m < DIM; ++m) {
    const int p0 = __builtin_popcount((unsigned)m & MT.vz0) & 1;
    const int p1 = __builtin_popcount((unsigned)m & MT.vz1) & 1;
    if (p0 && !p1)      t.slot[m] = (short)a++;
    else if (!p0 && p1) t.slot[m] = (short)b++;
    else if (p0 && p1)  t.slot[m] = (short)c++;
    else                t.slot[m] = -1;
  }
  return t;
}
__constant__ PermTab d_PT = make_perm();

// d = co*o + cp*q (complex), packed (re,im); 4 VOP3P instrs (verified r2-r16).
__device__ __forceinline__ f32x2 ampfma(f32x2 o, f32x2 q, f32x2 co, f32x2 cp) {
  f32x2 d;
  asm("v_pk_mul_f32 %0, %2, %1 op_sel:[0,0] op_sel_hi:[0,1]\n\t"
      "v_pk_fma_f32 %0, %2, %1, %0 op_sel:[1,1,0] op_sel_hi:[1,0,1] neg_lo:[1,0,0]\n\t"
      "v_pk_fma_f32 %0, %3, %4, %0 op_sel:[0,0,0] op_sel_hi:[0,1,1]\n\t"
      "v_pk_fma_f32 %0, %3, %4, %0 op_sel:[1,1,0] op_sel_hi:[1,0,1] neg_lo:[1,0,0]"
      : "=&v"(d)
      : "v"(o), "v"(co), "v"(cp), "v"(q));
  return d;
}

__device__ __forceinline__ float fxor(float x, unsigned m) {
  return __uint_as_float(__float_as_uint(x) ^ m);
}

// pack 4 f32 -> 4 fp8 e4m3 bytes (OCP) in a u32
__device__ __forceinline__ unsigned pk4_fp8(float a, float b, float c, float d) {
  int v = __builtin_amdgcn_cvt_pk_fp8_f32(a, b, 0, false);
  v = __builtin_amdgcn_cvt_pk_fp8_f32(c, d, v, true);
  return (unsigned)v;
}

__device__ __forceinline__ void gll16(const void* g, void* l) {
  __builtin_amdgcn_global_load_lds(
      (const __attribute__((address_space(1))) void*)g,
      (__attribute__((address_space(3))) void*)l, 16, 0, 0);
}

#define XSCALE 32.0f
#define WSCALE 16.0f
#define SINV   (1.0f / 262144.0f)   // 1/(32*16)^2

// ---------------------------------------------------------------------------
// K0+K1 merged. build_w blocks FIRST:
//   blocks [0, 832):     basis columns e_j -> W2[j][768 slots] fp8 (re,im)
//   blocks [832, 2880):  xcvt 8 rows/block: X f32 -> Xf8 (x*32) + xn2 = |x|^2
// ---------------------------------------------------------------------------
__global__ __launch_bounds__(256) void prep(const float* __restrict__ X,
                                            char* __restrict__ Xf8,
                                            float* __restrict__ xn2,
                                            const float* __restrict__ w,
                                            unsigned short* __restrict__ W2u) {
  __shared__ f32x4 UL4[NGATES];
  __shared__ f32x2 S0[DIM];
  __shared__ f32x2 S1[DIM];

  const int tid = threadIdx.x;

  if (blockIdx.x >= 832) {
    // ---- xcvt + row-norm: 8 rows/block, 32 lanes/row; 52 chunks of 16 ----
    const int row = (blockIdx.x - 832) * 8 + (tid >> 5);
    const int l32 = tid & 31;
    const float* src = X + (size_t)row * IN_DIM;
    char* dst = Xf8 + (size_t)row * KALLOC;
    float ssq = 0.0f;
    for (int c = l32; c < 52; c += 32) {
      u32x4 out;
      if (c < 49) {                                // 49*16 = 784 exactly
        f32x4 v0 = *(const f32x4*)(src + c * 16);
        f32x4 v1 = *(const f32x4*)(src + c * 16 + 4);
        f32x4 v2 = *(const f32x4*)(src + c * 16 + 8);
        f32x4 v3 = *(const f32x4*)(src + c * 16 + 12);
        ssq += v0.x * v0.x + v0.y * v0.y + v0.z * v0.z + v0.w * v0.w +
               v1.x * v1.x + v1.y * v1.y + v1.z * v1.z + v1.w * v1.w +
               v2.x * v2.x + v2.y * v2.y + v2.z * v2.z + v2.w * v2.w +
               v3.x * v3.x + v3.y * v3.y + v3.z * v3.z + v3.w * v3.w;
        out = u32x4{
          pk4_fp8(v0.x * XSCALE, v0.y * XSCALE, v0.z * XSCALE, v0.w * XSCALE),
          pk4_fp8(v1.x * XSCALE, v1.y * XSCALE, v1.z * XSCALE, v1.w * XSCALE),
          pk4_fp8(v2.x * XSCALE, v2.y * XSCALE, v2.z * XSCALE, v2.w * XSCALE),
          pk4_fp8(v3.x * XSCALE, v3.y * XSCALE, v3.z * XSCALE, v3.w * XSCALE)};
      } else {
        out = u32x4{0, 0, 0, 0};
      }
      *(u32x4*)(dst + c * 16) = out;
    }
#pragma unroll
    for (int off = 1; off < 32; off <<= 1) ssq += __shfl_xor(ssq, off);
    if (l32 == 0) xn2[row] = ssq;
    return;
  }

  // ---- build_w (gate loop verified r6-r16) ----
  if (tid < NGATES) {
    // qml.Rot(phi, theta, omega) = RZ(omega) RY(theta) RZ(phi)
    float phi = w[tid * 3 + 0], th = w[tid * 3 + 1], om = w[tid * 3 + 2];
    float ct = cosf(th * 0.5f), st = sinf(th * 0.5f);
    float aa = (phi + om) * 0.5f, bb = (phi - om) * 0.5f;
    float cA = cosf(aa), sA = sinf(aa), cB = cosf(bb), sB = sinf(bb);
    // u00 = e^{-ia} c ; u01 = -e^{+ib} s  (u11 = conj(u00), u10 = -conj(u01))
    UL4[tid] = f32x4{ ct * cA, -ct * sA, -st * cB, -st * sB };
  }

  const int j = blockIdx.x;                     // 0..831
  unsigned short* rowp = W2u + (size_t)j * NSLOT;

  if (j >= IN_DIM) {                            // zero pad rows
#pragma unroll
    for (int k = 0; k < 3; ++k) rowp[tid + k * 256] = 0;
    return;
  }

#pragma unroll
  for (int k = 0; k < 4; ++k) {
    const int m = tid + k * 256;
    S0[m] = f32x2{(m == j) ? 1.0f : 0.0f, 0.0f};
  }
  __syncthreads();

  for (int g = 0; g < NGATES; ++g) {
    const f32x2* src = (g & 1) ? S1 : S0;
    f32x2* dst = (g & 1) ? S0 : S1;
    const f32x4 A = UL4[g];
    const unsigned v = d_MT.v[g];
    const unsigned p = d_MT.p[g];
#pragma unroll
    for (int k = 0; k < 4; ++k) {
      const int m = tid + k * 256;
      f32x2 o = src[m];
      f32x2 q = src[m ^ (int)p];
      const unsigned sg = (unsigned)(__popc((int)((unsigned)m & v)) & 1) << 31;
      const f32x2 co = {A.x, fxor(A.y, sg)};
      const f32x2 cp = {fxor(A.z, sg), A.w};
      dst[m] = ampfma(o, q, co, cp);
    }
    __syncthreads();
  }

  const f32x2* fin = S0;   // 50 gates (even) -> final state back in S0
#pragma unroll
  for (int k = 0; k < 4; ++k) {
    const int m = tid + k * 256;
    const int s = d_PT.slot[m];
    f32x2 a = fin[m];
    if (s >= 0)
      rowp[s] = (unsigned short)(pk4_fp8(a.x * WSCALE, a.y * WSCALE,
                                         0.0f, 0.0f) & 0xffffu);
  }
}

// ---------------------------------------------------------------------------
// K2: transpose W2 [832 j][768 u16 slots] -> W2T [1536 fp8 rows][832 j bytes].
// Output row 2*slot+c holds component c (re/im) of slot across all j.
// ---------------------------------------------------------------------------
__global__ __launch_bounds__(256) void transpose_w(const unsigned* __restrict__ W2u32,
                                                   unsigned* __restrict__ W2Tu32) {
  __shared__ unsigned tile[64][33];   // [jr][sc]: 2 slots per u32
  const int j0 = blockIdx.x * 64;     // gridDim.x = 13
  const int s0 = blockIdx.y * 64;     // gridDim.y = 12 (slots)
  const int t = threadIdx.x;
#pragma unroll
  for (int i = 0; i < 8; ++i) {
    const int idx = i * 256 + t;
    const int jr = idx >> 5, sc = idx & 31;
    tile[jr][sc] = W2u32[(size_t)(j0 + jr) * (NSLOT / 2) + (s0 >> 1) + sc];
  }
  __syncthreads();
#pragma unroll
  for (int i = 0; i < 8; ++i) {
    const int idx = i * 256 + t;          // 2048 = 128 rows x 16 u32-cols
    const int rl = idx >> 4, jq = idx & 15;
    const int slot = rl >> 1, c = rl & 1;
    const int sc = slot >> 1, p = slot & 1;
    unsigned out = 0;
#pragma unroll
    for (int q = 0; q < 4; ++q) {
      const unsigned w32 = tile[jq * 4 + q][sc];
      const unsigned h = (w32 >> (16 * p)) & 0xffffu;
      out |= ((h >> (8 * c)) & 0xffu) << (8 * q);
    }
    const int orow = 2 * (s0 + slot) + c;
    W2Tu32[((size_t)orow * KALLOC + j0 + jq * 4) >> 2] = out;
  }
}

// ---------------------------------------------------------------------------
// K3 v15: r16 gemm structure, fp8 operands. 256x256 tile, 8 waves (2M x 4N),
// BK=64, 13 tiles, LDS 2 x (A 16KB + B 16KB) = 64KB -> 2 blocks/CU, all 384
// blocks resident (tail eliminated). 64B rows; swizzle chunk' = c ^ sw(row),
// sw(r) = (r&3)^((r>>2)&3) (fixes row+4 aliasing). One barrier/tile,
// mfma_f32_16x16x32_fp8_fp8 (bf16 rate, half LDS bytes).
// ---------------------------------------------------------------------------
__global__ __launch_bounds__(512) void gemm_fused(const char* __restrict__ Xf8,
                                                  const char* __restrict__ W2T,
                                                  float* __restrict__ accb) {
  __shared__ u32x4 lds4[4096];   // 64 KB
  char* lds = (char*)lds4;

  const int tid = threadIdx.x;
  const int orig = blockIdx.x;                    // 384 blocks
  const int bx = (orig & 7) * 48 + (orig >> 3);   // XCD-chunked (384%8==0)
  const int mb = bx / NB, nb = bx % NB;
  const int m0 = mb * 256, n0 = nb * 256;
  const int lane = tid & 63, wv = tid >> 6;
  const int wm = wv >> 2, wn = wv & 3;

  // stage lane geometry: unit g = 1KB = 16 rows x 64B. lane l -> row_local
  // l>>2, chunk' = l&3; source chunk c = (l&3) ^ sw(l>>2),
  // sw(r) = (r&3)^((r>>2)&3)  ->  phys chunk' = c ^ sw(row).
  const int rl = lane >> 2;
  const int csrc = (lane & 3) ^ (rl & 3) ^ ((rl >> 2) & 3);

  auto stage = [&](int t) {
    char* Ab = lds + (t & 1) * 32768;
    char* Bb = Ab + 16384;
    const int col = t * 64 + csrc * 16;
#pragma unroll
    for (int i = 0; i < 2; ++i) {                 // A: 2 units/wave (16 total)
      const int g = wv * 2 + i;
      const int row = g * 16 + rl;
      gll16(Xf8 + (size_t)(m0 + row) * KALLOC + col, Ab + g * 1024);
    }
#pragma unroll
    for (int i = 0; i < 2; ++i) {                 // B: 2 units/wave
      const int g = wv * 2 + i;
      const int row = g * 16 + rl;
      gll16(W2T + (size_t)(n0 + row) * KALLOC + col, Bb + g * 1024);
    }
  };

  stage(0);
  asm volatile("s_waitcnt vmcnt(0)" ::: "memory");
  __builtin_amdgcn_s_barrier();

  f32x4 acc[8][4];
#pragma unroll
  for (int fm = 0; fm < 8; ++fm)
#pragma unroll
    for (int fn = 0; fn < 4; ++fn) acc[fm][fn] = f32x4{0, 0, 0, 0};

  const int kc = lane >> 4;                       // k-chunk-of-8 within K=32

  for (int t = 0; t < NT; ++t) {
    const char* Ab = lds + (t & 1) * 32768;
    const char* Bb = Ab + 16384;

    long af0[8], bf0[4], af1[8], bf1[4];
    // fragment byte offset within row: kb = kh*4+kc ->
    //   ((kb>>1) ^ sw(row))*16 + (kb&1)*8
#pragma unroll
    for (int f = 0; f < 8; ++f) {
      const int ar = wm * 128 + f * 16 + (lane & 15);
      const int sw = (ar & 3) ^ ((ar >> 2) & 3);
      af0[f] = *(const long*)(Ab + ar * 64 + (((kc >> 1) ^ sw) * 16) + (kc & 1) * 8);
    }
#pragma unroll
    for (int f = 0; f < 4; ++f) {
      const int br = wn * 64 + f * 16 + (lane & 15);
      const int sw = (br & 3) ^ ((br >> 2) & 3);
      bf0[f] = *(const long*)(Bb + br * 64 + (((kc >> 1) ^ sw) * 16) + (kc & 1) * 8);
    }
    if (t < NT - 1) stage(t + 1);                 // -> other buffer (safe)
#pragma unroll
    for (int f = 0; f < 8; ++f) {
      const int ar = wm * 128 + f * 16 + (lane & 15);
      const int sw = (ar & 3) ^ ((ar >> 2) & 3);
      const int kb = 4 + kc;
      af1[f] = *(const long*)(Ab + ar * 64 + (((kb >> 1) ^ sw) * 16) + (kb & 1) * 8);
    }
#pragma unroll
    for (int f = 0; f < 4; ++f) {
      const int br = wn * 64 + f * 16 + (lane & 15);
      const int sw = (br & 3) ^ ((br >> 2) & 3);
      const int kb = 4 + kc;
      bf1[f] = *(const long*)(Bb + br * 64 + (((kb >> 1) ^ sw) * 16) + (kb & 1) * 8);
    }

    __builtin_amdgcn_s_setprio(1);
#pragma unroll
    for (int fm = 0; fm < 8; ++fm)
#pragma unroll
      for (int fn = 0; fn < 4; ++fn)
        acc[fm][fn] = __builtin_amdgcn_mfma_f32_16x16x32_fp8_fp8(
            af0[fm], bf0[fn], acc[fm][fn], 0, 0, 0);
    __builtin_amdgcn_s_setprio(0);

    __builtin_amdgcn_s_setprio(1);
#pragma unroll
    for (int fm = 0; fm < 8; ++fm)
#pragma unroll
      for (int fn = 0; fn < 4; ++fn)
        acc[fm][fn] = __builtin_amdgcn_mfma_f32_16x16x32_fp8_fp8(
            af1[fm], bf1[fn], acc[fm][fn], 0, 0, 0);
    __builtin_amdgcn_s_setprio(0);

    if (t < NT - 1) {
      asm volatile("s_waitcnt vmcnt(0)" ::: "memory");  // next tile landed
      __builtin_amdgcn_sched_barrier(0);
      __builtin_amdgcn_s_barrier();
    }
  }

  // ---- epilogue: per-sample sum |out|^2 for this nb (group-uniform) ----
#pragma unroll
  for (int fm = 0; fm < 8; ++fm) {
    float sn[4] = {0, 0, 0, 0};
#pragma unroll
    for (int fn = 0; fn < 4; ++fn) {
#pragma unroll
      for (int r = 0; r < 4; ++r) {
        const float vv = acc[fm][fn][r];
        sn[r] = fmaf(vv, vv, sn[r]);
      }
    }
#pragma unroll
    for (int off = 1; off < 16; off <<= 1) {
#pragma unroll
      for (int r = 0; r < 4; ++r) sn[r] += __shfl_xor(sn[r], off);
    }
    if ((lane & 15) == 0) {
#pragma unroll
      for (int r = 0; r < 4; ++r) {
        const int m = m0 + wm * 128 + fm * 16 + (lane >> 4) * 4 + r;
        accb[(size_t)nb * BATCH + m] = sn[r];
      }
    }
  }
}

// ---------------------------------------------------------------------------
// K4/K5: per-sample loss + mean reduction. S scaled by 1/(32*16)^2.
// ---------------------------------------------------------------------------
__global__ __launch_bounds__(256) void loss_partial(const float* __restrict__ accb,
                                                    const float* __restrict__ xn2,
                                                    const int* __restrict__ y,
                                                    float* __restrict__ partial) {
  const int s = blockIdx.x * 256 + threadIdx.x;
  const float SA = (accb[0 * BATCH + s] + accb[1 * BATCH + s]) * SINV;
  const float SB = (accb[2 * BATCH + s] + accb[3 * BATCH + s]) * SINV;
  const float SC = (accb[4 * BATCH + s] + accb[5 * BATCH + s]) * SINV;
  const float n2 = xn2[s];
  const float z0 = n2 - 2.0f * (SA + SC);
  const float z1 = n2 - 2.0f * (SB + SC);
  const float inv = 1.0f / n2;
  const float l0 = z0 * inv, l1 = z1 * inv;
  const float mx = fmaxf(l0, l1);
  const float lse = mx + logf(expf(l0 - mx) + expf(l1 - mx));
  float loss = lse - ((y[s] == 0) ? l0 : l1);

  __shared__ float sm[256];
  sm[threadIdx.x] = loss;
  __syncthreads();
  for (int st = 128; st > 0; st >>= 1) {
    if (threadIdx.x < st) sm[threadIdx.x] += sm[threadIdx.x + st];
    __syncthreads();
  }
  if (threadIdx.x == 0) partial[blockIdx.x] = sm[0];
}

__global__ __launch_bounds__(64) void loss_final(const float* __restrict__ partial,
                                                 float* __restrict__ out) {
  float v = partial[threadIdx.x];
#pragma unroll
  for (int off = 1; off < 64; off <<= 1) v += __shfl_xor(v, off);
  if (threadIdx.x == 0) out[0] = v * (1.0f / (float)BATCH);
}

// ---------------------------------------------------------------------------
extern "C" void kernel_launch(void* const* d_in, const int* in_sizes, int n_in,
                              void* d_out, int out_size, void* d_ws, size_t ws_size,
                              hipStream_t stream) {
  const float* x = (const float*)d_in[0];   // [16384, 784] f32
  const float* w = (const float*)d_in[1];   // [5, 10, 3] f32
  const int*   y = (const int*)d_in[2];     // [16384] i32

  char* ws = (char*)d_ws;
  char*     Xf8  = ws;                               // 16384*832 = 13.63 MB
  unsigned short* W2u = (unsigned short*)(ws + 13631488);  // 832*768*2 = 1.28 MB
  char*     W2Tu = ws + 14909440;                    // 1536*832 = 1.28 MB
  float*    xn2  = (float*)(ws + 16187392);          // 64 KB
  float*    accb = (float*)(ws + 16252928);          // 6*16384*4 = 384 KB
  float* partial = (float*)(ws + 16646144);          // 64 f32

  prep<<<2880, 256, 0, stream>>>(x, Xf8, xn2, w, W2u);
  transpose_w<<<dim3(13, 12), 256, 0, stream>>>((const unsigned*)W2u,
                                                (unsigned*)W2Tu);
  gemm_fused<<<384, 512, 0, stream>>>(Xf8, W2Tu, accb);
  loss_partial<<<BATCH / 256, 256, 0, stream>>>(accb, xn2, y, partial);
  loss_final<<<1, 64, 0, stream>>>(partial, (float*)d_out);
}

// Round 18
// 79.104 us; speedup vs baseline: 1.7038x; 1.1051x over previous
//
#include <hip/hip_runtime.h>
#include <type_traits>

#define NQ 10
#define N_DEPTH 5
#define DIM 1024
#define BATCH 16384
#define IN_DIM 784
#define NGATES 50
#define KALLOC 832    // fp8 row length (13*64); cols >=784 zero
#define NT 13         // K-tiles of 64
#define NSLOT 768     // kept complex amp slots (p0|p1), group-blocked
#define NB 12         // gemm n-blocks (1536 fp8 rows / 128)

typedef float f32x2 __attribute__((ext_vector_type(2)));
typedef float f32x4 __attribute__((ext_vector_type(4)));
typedef unsigned u32x4 __attribute__((ext_vector_type(4)));

// ---------------------------------------------------------------------------
// Compile-time mask tables: CNOTs absorbed into GF(2)-linear index transform.
// ---------------------------------------------------------------------------
struct MaskTab {
  unsigned v[NGATES];
  unsigned p[NGATES];
  unsigned vz0, vz1;
};

constexpr MaskTab make_masks() {
  MaskTab t{};
  unsigned v[NQ], p[NQ];
  for (int i = 0; i < NQ; ++i) { v[i] = 1u << (9 - i); p[i] = 1u << (9 - i); }
  for (int d = 0; d < N_DEPTH; ++d) {
    for (int i = 0; i < NQ; ++i) {
      int c = i, tt = (i + 1) % NQ;
      v[tt] ^= v[c];
      p[c]  ^= p[tt];
    }
    for (int i = 0; i < NQ; ++i) {
      t.v[d * NQ + i] = v[i];
      t.p[d * NQ + i] = p[i];
    }
  }
  t.vz0 = v[0];
  t.vz1 = v[1];
  return t;
}

constexpr MaskTab MT = make_masks();
__constant__ MaskTab d_MT = make_masks();

// Permutation: state m -> slot. Groups of 256 complex slots:
//   A [0,256): p0=1,p1=0   B [256,512): p0=0,p1=1   C [512,768): p0=1,p1=1
// z0 = n2 - 2(SA+SC), z1 = n2 - 2(SB+SC); n2 = |x|^2 exact (unitarity).
struct PermTab { short slot[DIM]; };
constexpr PermTab make_perm() {
  PermTab t{};
  int a = 0, b = 256, c = 512;
  for (int m = 0; m < DIM; ++m) {
    const int p0 = __builtin_popcount((unsigned)m & MT.vz0) & 1;
    const int p1 = __builtin_popcount((unsigned)m & MT.vz1) & 1;
    if (p0 && !p1)      t.slot[m] = (short)a++;
    else if (!p0 && p1) t.slot[m] = (short)b++;
    else if (p0 && p1)  t.slot[m] = (short)c++;
    else                t.slot[m] = -1;
  }
  return t;
}
__constant__ PermTab d_PT = make_perm();

// d = co*o + cp*q (complex), packed (re,im); 4 VOP3P instrs (verified r2-r17).
__device__ __forceinline__ f32x2 ampfma(f32x2 o, f32x2 q, f32x2 co, f32x2 cp) {
  f32x2 d;
  asm("v_pk_mul_f32 %0, %2, %1 op_sel:[0,0] op_sel_hi:[0,1]\n\t"
      "v_pk_fma_f32 %0, %2, %1, %0 op_sel:[1,1,0] op_sel_hi:[1,0,1] neg_lo:[1,0,0]\n\t"
      "v_pk_fma_f32 %0, %3, %4, %0 op_sel:[0,0,0] op_sel_hi:[0,1,1]\n\t"
      "v_pk_fma_f32 %0, %3, %4, %0 op_sel:[1,1,0] op_sel_hi:[1,0,1] neg_lo:[1,0,0]"
      : "=&v"(d)
      : "v"(o), "v"(co), "v"(cp), "v"(q));
  return d;
}

__device__ __forceinline__ float fxor(float x, unsigned m) {
  return __uint_as_float(__float_as_uint(x) ^ m);
}

// pack 4 f32 -> 4 fp8 e4m3 bytes (OCP) in a u32
__device__ __forceinline__ unsigned pk4_fp8(float a, float b, float c, float d) {
  int v = __builtin_amdgcn_cvt_pk_fp8_f32(a, b, 0, false);
  v = __builtin_amdgcn_cvt_pk_fp8_f32(c, d, v, true);
  return (unsigned)v;
}

__device__ __forceinline__ void gll16(const void* g, void* l) {
  __builtin_amdgcn_global_load_lds(
      (const __attribute__((address_space(1))) void*)g,
      (__attribute__((address_space(3))) void*)l, 16, 0, 0);
}

#define XSCALE 32.0f
#define WSCALE 16.0f
#define SINV   (1.0f / 262144.0f)   // 1/(32*16)^2

// ---------------------------------------------------------------------------
// K0+K1 merged. build_w blocks FIRST:
//   blocks [0, 832):     basis columns e_j -> W2T[1536 rows][832 j] fp8,
//                        written DIRECTLY (scatter bytes; no transpose pass)
//   blocks [832, 2880):  xcvt 8 rows/block: X f32 -> Xf8 (x*32) + xn2 = |x|^2
// ---------------------------------------------------------------------------
__global__ __launch_bounds__(256) void prep(const float* __restrict__ X,
                                            char* __restrict__ Xf8,
                                            float* __restrict__ xn2,
                                            const float* __restrict__ w,
                                            char* __restrict__ W2T) {
  __shared__ f32x4 UL4[NGATES];
  __shared__ f32x2 S0[DIM];
  __shared__ f32x2 S1[DIM];

  const int tid = threadIdx.x;

  if (blockIdx.x >= 832) {
    // ---- xcvt + row-norm: 8 rows/block, 32 lanes/row; 52 chunks of 16 ----
    const int row = (blockIdx.x - 832) * 8 + (tid >> 5);
    const int l32 = tid & 31;
    const float* src = X + (size_t)row * IN_DIM;
    char* dst = Xf8 + (size_t)row * KALLOC;
    float ssq = 0.0f;
    for (int c = l32; c < 52; c += 32) {
      u32x4 out;
      if (c < 49) {                                // 49*16 = 784 exactly
        f32x4 v0 = *(const f32x4*)(src + c * 16);
        f32x4 v1 = *(const f32x4*)(src + c * 16 + 4);
        f32x4 v2 = *(const f32x4*)(src + c * 16 + 8);
        f32x4 v3 = *(const f32x4*)(src + c * 16 + 12);
        ssq += v0.x * v0.x + v0.y * v0.y + v0.z * v0.z + v0.w * v0.w +
               v1.x * v1.x + v1.y * v1.y + v1.z * v1.z + v1.w * v1.w +
               v2.x * v2.x + v2.y * v2.y + v2.z * v2.z + v2.w * v2.w +
               v3.x * v3.x + v3.y * v3.y + v3.z * v3.z + v3.w * v3.w;
        out = u32x4{
          pk4_fp8(v0.x * XSCALE, v0.y * XSCALE, v0.z * XSCALE, v0.w * XSCALE),
          pk4_fp8(v1.x * XSCALE, v1.y * XSCALE, v1.z * XSCALE, v1.w * XSCALE),
          pk4_fp8(v2.x * XSCALE, v2.y * XSCALE, v2.z * XSCALE, v2.w * XSCALE),
          pk4_fp8(v3.x * XSCALE, v3.y * XSCALE, v3.z * XSCALE, v3.w * XSCALE)};
      } else {
        out = u32x4{0, 0, 0, 0};
      }
      *(u32x4*)(dst + c * 16) = out;
    }
#pragma unroll
    for (int off = 1; off < 32; off <<= 1) ssq += __shfl_xor(ssq, off);
    if (l32 == 0) xn2[row] = ssq;
    return;
  }

  // ---- build_w (gate loop verified r6-r17) ----
  if (tid < NGATES) {
    // qml.Rot(phi, theta, omega) = RZ(omega) RY(theta) RZ(phi)
    float phi = w[tid * 3 + 0], th = w[tid * 3 + 1], om = w[tid * 3 + 2];
    float ct = cosf(th * 0.5f), st = sinf(th * 0.5f);
    float aa = (phi + om) * 0.5f, bb = (phi - om) * 0.5f;
    float cA = cosf(aa), sA = sinf(aa), cB = cosf(bb), sB = sinf(bb);
    // u00 = e^{-ia} c ; u01 = -e^{+ib} s  (u11 = conj(u00), u10 = -conj(u01))
    UL4[tid] = f32x4{ ct * cA, -ct * sA, -st * cB, -st * sB };
  }

  const int j = blockIdx.x;                     // 0..831

  if (j >= IN_DIM) {                            // zero pad columns j>=784
#pragma unroll
    for (int k = 0; k < 3; ++k) {
      const int s = tid + k * 256;              // slot 0..767
      W2T[(size_t)(2 * s) * KALLOC + j] = 0;
      W2T[(size_t)(2 * s + 1) * KALLOC + j] = 0;
    }
    return;
  }

#pragma unroll
  for (int k = 0; k < 4; ++k) {
    const int m = tid + k * 256;
    S0[m] = f32x2{(m == j) ? 1.0f : 0.0f, 0.0f};
  }
  __syncthreads();

  for (int g = 0; g < NGATES; ++g) {
    const f32x2* src = (g & 1) ? S1 : S0;
    f32x2* dst = (g & 1) ? S0 : S1;
    const f32x4 A = UL4[g];
    const unsigned v = d_MT.v[g];
    const unsigned p = d_MT.p[g];
#pragma unroll
    for (int k = 0; k < 4; ++k) {
      const int m = tid + k * 256;
      f32x2 o = src[m];
      f32x2 q = src[m ^ (int)p];
      const unsigned sg = (unsigned)(__popc((int)((unsigned)m & v)) & 1) << 31;
      const f32x2 co = {A.x, fxor(A.y, sg)};
      const f32x2 cp = {fxor(A.z, sg), A.w};
      dst[m] = ampfma(o, q, co, cp);
    }
    __syncthreads();
  }

  const f32x2* fin = S0;   // 50 gates (even) -> final state back in S0
#pragma unroll
  for (int k = 0; k < 4; ++k) {
    const int m = tid + k * 256;
    const int s = d_PT.slot[m];
    f32x2 a = fin[m];
    if (s >= 0) {
      const unsigned pk = pk4_fp8(a.x * WSCALE, a.y * WSCALE, 0.0f, 0.0f);
      W2T[(size_t)(2 * s) * KALLOC + j] = (char)(pk & 0xffu);
      W2T[(size_t)(2 * s + 1) * KALLOC + j] = (char)((pk >> 8) & 0xffu);
    }
  }
}

// ---------------------------------------------------------------------------
// K3 v16: fp8 gemm, BN 256->128 for residency: 768 blocks (64mb x 12nb),
// LDS 2 x (A 16KB + B 8KB) = 48KB -> 3 blocks/CU, 768 = 3*256 exact fill
// (24 waves/CU; other blocks cover barrier/drain stalls). 8 waves 2M x 4N,
// wave tile 128x32, acc[8][2]. BK=64, 13 tiles, one barrier/tile, swizzle
// chunk' = c ^ sw(row), sw(r) = (r&3)^((r>>2)&3) (verified r17, 2-way benign).
// ---------------------------------------------------------------------------
__global__ __launch_bounds__(512) void gemm_fused(const char* __restrict__ Xf8,
                                                  const char* __restrict__ W2T,
                                                  float* __restrict__ accb) {
  __shared__ u32x4 lds4[3072];   // 48 KB
  char* lds = (char*)lds4;

  const int tid = threadIdx.x;
  const int orig = blockIdx.x;                    // 768 blocks
  const int bx = (orig & 7) * 96 + (orig >> 3);   // XCD-chunked (768%8==0)
  const int mb = bx / NB, nb = bx % NB;
  const int m0 = mb * 256, n0 = nb * 128;
  const int lane = tid & 63, wv = tid >> 6;
  const int wm = wv >> 2, wn = wv & 3;

  // stage lane geometry: unit g = 1KB = 16 rows x 64B. lane l -> row_local
  // l>>2, chunk' = l&3; source chunk c = (l&3) ^ sw(l>>2),
  // sw(r) = (r&3)^((r>>2)&3)  ->  phys chunk' = c ^ sw(row).
  const int rl = lane >> 2;
  const int csrc = (lane & 3) ^ (rl & 3) ^ ((rl >> 2) & 3);

  auto stage = [&](int t) {
    char* Ab = lds + (t & 1) * 24576;
    char* Bb = Ab + 16384;
    const int col = t * 64 + csrc * 16;
#pragma unroll
    for (int i = 0; i < 2; ++i) {                 // A: 2 units/wave (16 total)
      const int g = wv * 2 + i;
      const int row = g * 16 + rl;
      gll16(Xf8 + (size_t)(m0 + row) * KALLOC + col, Ab + g * 1024);
    }
    {                                             // B: 1 unit/wave (8 total)
      const int row = wv * 16 + rl;
      gll16(W2T + (size_t)(n0 + row) * KALLOC + col, Bb + wv * 1024);
    }
  };

  stage(0);
  asm volatile("s_waitcnt vmcnt(0)" ::: "memory");
  __builtin_amdgcn_s_barrier();

  f32x4 acc[8][2];
#pragma unroll
  for (int fm = 0; fm < 8; ++fm)
#pragma unroll
    for (int fn = 0; fn < 2; ++fn) acc[fm][fn] = f32x4{0, 0, 0, 0};

  const int kc = lane >> 4;                       // k-chunk-of-8 within K=32

  for (int t = 0; t < NT; ++t) {
    const char* Ab = lds + (t & 1) * 24576;
    const char* Bb = Ab + 16384;

    long af0[8], bf0[2], af1[8], bf1[2];
    // fragment byte offset within row: kb = kh*4+kc ->
    //   ((kb>>1) ^ sw(row))*16 + (kb&1)*8
#pragma unroll
    for (int f = 0; f < 8; ++f) {
      const int ar = wm * 128 + f * 16 + (lane & 15);
      const int sw = (ar & 3) ^ ((ar >> 2) & 3);
      af0[f] = *(const long*)(Ab + ar * 64 + (((kc >> 1) ^ sw) * 16) + (kc & 1) * 8);
    }
#pragma unroll
    for (int f = 0; f < 2; ++f) {
      const int br = wn * 32 + f * 16 + (lane & 15);
      const int sw = (br & 3) ^ ((br >> 2) & 3);
      bf0[f] = *(const long*)(Bb + br * 64 + (((kc >> 1) ^ sw) * 16) + (kc & 1) * 8);
    }
    if (t < NT - 1) stage(t + 1);                 // -> other buffer (safe)
#pragma unroll
    for (int f = 0; f < 8; ++f) {
      const int ar = wm * 128 + f * 16 + (lane & 15);
      const int sw = (ar & 3) ^ ((ar >> 2) & 3);
      const int kb = 4 + kc;
      af1[f] = *(const long*)(Ab + ar * 64 + (((kb >> 1) ^ sw) * 16) + (kb & 1) * 8);
    }
#pragma unroll
    for (int f = 0; f < 2; ++f) {
      const int br = wn * 32 + f * 16 + (lane & 15);
      const int sw = (br & 3) ^ ((br >> 2) & 3);
      const int kb = 4 + kc;
      bf1[f] = *(const long*)(Bb + br * 64 + (((kb >> 1) ^ sw) * 16) + (kb & 1) * 8);
    }

    __builtin_amdgcn_s_setprio(1);
#pragma unroll
    for (int fm = 0; fm < 8; ++fm)
#pragma unroll
      for (int fn = 0; fn < 2; ++fn)
        acc[fm][fn] = __builtin_amdgcn_mfma_f32_16x16x32_fp8_fp8(
            af0[fm], bf0[fn], acc[fm][fn], 0, 0, 0);
    __builtin_amdgcn_s_setprio(0);

    __builtin_amdgcn_s_setprio(1);
#pragma unroll
    for (int fm = 0; fm < 8; ++fm)
#pragma unroll
      for (int fn = 0; fn < 2; ++fn)
        acc[fm][fn] = __builtin_amdgcn_mfma_f32_16x16x32_fp8_fp8(
            af1[fm], bf1[fn], acc[fm][fn], 0, 0, 0);
    __builtin_amdgcn_s_setprio(0);

    if (t < NT - 1) {
      asm volatile("s_waitcnt vmcnt(0)" ::: "memory");  // next tile landed
      __builtin_amdgcn_sched_barrier(0);
      __builtin_amdgcn_s_barrier();
    }
  }

  // ---- epilogue: per-sample sum |out|^2 for this nb (group-uniform) ----
#pragma unroll
  for (int fm = 0; fm < 8; ++fm) {
    float sn[4] = {0, 0, 0, 0};
#pragma unroll
    for (int fn = 0; fn < 2; ++fn) {
#pragma unroll
      for (int r = 0; r < 4; ++r) {
        const float vv = acc[fm][fn][r];
        sn[r] = fmaf(vv, vv, sn[r]);
      }
    }
#pragma unroll
    for (int off = 1; off < 16; off <<= 1) {
#pragma unroll
      for (int r = 0; r < 4; ++r) sn[r] += __shfl_xor(sn[r], off);
    }
    if ((lane & 15) == 0) {
#pragma unroll
      for (int r = 0; r < 4; ++r) {
        const int m = m0 + wm * 128 + fm * 16 + (lane >> 4) * 4 + r;
        accb[(size_t)nb * BATCH + m] = sn[r];
      }
    }
  }
}

// ---------------------------------------------------------------------------
// K4/K5: per-sample loss + mean reduction. S scaled by 1/(32*16)^2.
// Groups: A = nb 0-3, B = nb 4-7, C = nb 8-11.
// ---------------------------------------------------------------------------
__global__ __launch_bounds__(256) void loss_partial(const float* __restrict__ accb,
                                                    const float* __restrict__ xn2,
                                                    const int* __restrict__ y,
                                                    float* __restrict__ partial) {
  const int s = blockIdx.x * 256 + threadIdx.x;
  float SA = 0.0f, SB = 0.0f, SC = 0.0f;
#pragma unroll
  for (int k = 0; k < 4; ++k) {
    SA += accb[(size_t)(0 + k) * BATCH + s];
    SB += accb[(size_t)(4 + k) * BATCH + s];
    SC += accb[(size_t)(8 + k) * BATCH + s];
  }
  SA *= SINV; SB *= SINV; SC *= SINV;
  const float n2 = xn2[s];
  const float z0 = n2 - 2.0f * (SA + SC);
  const float z1 = n2 - 2.0f * (SB + SC);
  const float inv = 1.0f / n2;
  const float l0 = z0 * inv, l1 = z1 * inv;
  const float mx = fmaxf(l0, l1);
  const float lse = mx + logf(expf(l0 - mx) + expf(l1 - mx));
  float loss = lse - ((y[s] == 0) ? l0 : l1);

  __shared__ float sm[256];
  sm[threadIdx.x] = loss;
  __syncthreads();
  for (int st = 128; st > 0; st >>= 1) {
    if (threadIdx.x < st) sm[threadIdx.x] += sm[threadIdx.x + st];
    __syncthreads();
  }
  if (threadIdx.x == 0) partial[blockIdx.x] = sm[0];
}

__global__ __launch_bounds__(64) void loss_final(const float* __restrict__ partial,
                                                 float* __restrict__ out) {
  float v = partial[threadIdx.x];
#pragma unroll
  for (int off = 1; off < 64; off <<= 1) v += __shfl_xor(v, off);
  if (threadIdx.x == 0) out[0] = v * (1.0f / (float)BATCH);
}

// ---------------------------------------------------------------------------
extern "C" void kernel_launch(void* const* d_in, const int* in_sizes, int n_in,
                              void* d_out, int out_size, void* d_ws, size_t ws_size,
                              hipStream_t stream) {
  const float* x = (const float*)d_in[0];   // [16384, 784] f32
  const float* w = (const float*)d_in[1];   // [5, 10, 3] f32
  const int*   y = (const int*)d_in[2];     // [16384] i32

  char* ws = (char*)d_ws;
  char*     Xf8  = ws;                               // 16384*832 = 13.63 MB
  char*     W2Tu = ws + 13631488;                    // 1536*832 = 1.28 MB
  float*    xn2  = (float*)(ws + 14909440);          // 64 KB
  float*    accb = (float*)(ws + 14975232);          // 12*16384*4 = 768 KB
  float* partial = (float*)(ws + 15761408);          // 64 f32

  prep<<<2880, 256, 0, stream>>>(x, Xf8, xn2, w, W2Tu);
  gemm_fused<<<768, 512, 0, stream>>>(Xf8, W2Tu, accb);
  loss_partial<<<BATCH / 256, 256, 0, stream>>>(accb, xn2, y, partial);
  loss_final<<<1, 64, 0, stream>>>(partial, (float*)d_out);
}